// Round 4
// baseline (221.823 us; speedup 1.0000x reference)
//
#include <hip/hip_runtime.h>
#include <hip/hip_bf16.h>

typedef _Float16 half8 __attribute__((ext_vector_type(8)));
typedef _Float16 half4 __attribute__((ext_vector_type(4)));
typedef _Float16 half2v __attribute__((ext_vector_type(2)));
typedef float f32x4 __attribute__((ext_vector_type(4)));

namespace {

constexpr int INW  = 87;
constexpr int ROWS = 64;    // rows per block
constexpr int NT   = 512;   // 8 waves: 2 row-waves x 4 col-waves

// ws layout (halves), all K padded to multiple of 32, n-major [256][K]
constexpr long O_FC1 = 0;        // [256][96], k<77 real
constexpr long O_FC2 = 24576;    // [256][32], k<10 real
constexpr long O_ENC = 32768;    // [256][256]
constexpr long O_HDS = 98304;    // 8 x [256][256]
constexpr long O_DEC = 622592;   // [256][256]
constexpr long O_FC3 = 688128;   // [256][256]
constexpr long W_TOTAL = 753664; // halves (1.44 MB)

__device__ __forceinline__ int aidx(int row, int col) {
  return row * 256 + ((((col >> 3) ^ (row & 7)) << 3) | (col & 7));
}

// -------- prep: transpose+convert f32 [K][256] -> fp16 [256][Kpad] --------
__global__ __launch_bounds__(256)
void prep_w(const float* __restrict__ Wfc1, const float* __restrict__ Wfc2,
            const float* __restrict__ Wenc, const float* __restrict__ Whds,
            const float* __restrict__ Wdec, const float* __restrict__ Wfc3,
            _Float16* __restrict__ ws)
{
  const long t = (long)blockIdx.x * 256 + threadIdx.x;
  const long e = t * 4;
  if (e >= W_TOTAL) return;
  const float* src; int K, Kreal; long base;
  if (e < O_FC2)      { src = Wfc1; K = 96;  Kreal = 77;  base = O_FC1; }
  else if (e < O_ENC) { src = Wfc2; K = 32;  Kreal = 10;  base = O_FC2; }
  else if (e < O_HDS) { src = Wenc; K = 256; Kreal = 256; base = O_ENC; }
  else if (e < O_DEC) { const long le = e - O_HDS; const int h = (int)(le >> 16);
                        src = Whds + ((long)h << 16); K = 256; Kreal = 256;
                        base = O_HDS + ((long)h << 16); }
  else if (e < O_FC3) { src = Wdec; K = 256; Kreal = 256; base = O_DEC; }
  else                { src = Wfc3; K = 256; Kreal = 256; base = O_FC3; }
  const long le = e - base;
  const int n = (int)(le / K), k0 = (int)(le % K);
  half4 v;
#pragma unroll
  for (int j = 0; j < 4; ++j) {
    const int k = k0 + j;
    v[j] = (_Float16)((k < Kreal) ? src[(size_t)k * 256 + n] : 0.f);
  }
  *(half4*)&ws[e] = v;
}

// -------- per-wave GEMM: C[32 rows x 64 cols] = A[32 x K] * Wt[n][K]^T --------
template<int KS>
__device__ __forceinline__ void gemmT(const _Float16* __restrict__ A,
                                      const _Float16* __restrict__ Wt,
                                      const float* __restrict__ bias,
                                      int acol0, int l15, int l4,
                                      int rbase, int cbase,
                                      f32x4 (&acc)[2][4])
{
#pragma unroll
  for (int nt = 0; nt < 4; ++nt) {
    const float bv = bias[cbase + nt * 16 + l15];
#pragma unroll
    for (int mt = 0; mt < 2; ++mt) acc[mt][nt] = { bv, bv, bv, bv };
  }
  constexpr int Klen = KS * 32;
#pragma unroll
  for (int ks = 0; ks < KS; ++ks) {
    const int k0 = ks * 32 + l4 * 8;
    half8 af[2], bf[4];
#pragma unroll
    for (int mt = 0; mt < 2; ++mt) {
      const int row = rbase + mt * 16 + l15;
      const int col = acol0 + k0;                       // 8-aligned
      af[mt] = *(const half8*)&A[row * 256 + (((col >> 3) ^ (row & 7)) << 3)];
    }
#pragma unroll
    for (int nt = 0; nt < 4; ++nt) {
      const int n = cbase + nt * 16 + l15;
      bf[nt] = *(const half8*)&Wt[(long)n * Klen + k0];
    }
#pragma unroll
    for (int mt = 0; mt < 2; ++mt)
#pragma unroll
      for (int nt = 0; nt < 4; ++nt)
        acc[mt][nt] = __builtin_amdgcn_mfma_f32_16x16x32_f16(
            af[mt], bf[nt], acc[mt][nt], 0, 0, 0);
  }
}

__device__ __forceinline__ void writeA(_Float16* __restrict__ A,
                                       const f32x4 (&acc)[2][4],
                                       int l15, int l4, int rbase, int cbase,
                                       bool relu)
{
#pragma unroll
  for (int mt = 0; mt < 2; ++mt)
#pragma unroll
    for (int nt = 0; nt < 4; ++nt)
#pragma unroll
      for (int r = 0; r < 4; ++r) {
        float v = acc[mt][nt][r];
        if (relu) v = fmaxf(v, 0.f);
        const int row = rbase + mt * 16 + l4 * 4 + r;
        const int col = cbase + nt * 16 + l15;
        A[aidx(row, col)] = (_Float16)v;
      }
}

__global__ __launch_bounds__(NT, 2)
void fused_mfma(const float* __restrict__ x,
                const float* __restrict__ bfc1, const float* __restrict__ bfc2,
                const float* __restrict__ benc, const float* __restrict__ bhds,
                const float* __restrict__ bdec, const float* __restrict__ bfc3,
                const float* __restrict__ Wq,  const float* __restrict__ bq,
                const int* __restrict__ agent,
                const _Float16* __restrict__ ws,
                float* __restrict__ out)
{
  __shared__ _Float16 A[ROWS * 256];     // 32 KB
  __shared__ float sp[2][4][ROWS];       // 2 KB

  const int tid  = (int)threadIdx.x;
  const int lane = tid & 63;
  const int wave = tid >> 6;
  const int wr   = wave >> 2;       // 0..1 : 32-row stripe
  const int wc   = wave & 3;        // 0..3 : 64-col stripe
  const int l15  = lane & 15;
  const int l4   = lane >> 4;
  const int rbase = wr * 32;
  const int cbase = wc * 64;
  const int row0 = (int)blockIdx.x * ROWS;
  const int a = agent[0];

  // ---- build A0 [64][128]: cols 0..76 enc-in, 96..105 dec-others, rest 0 ----
  for (int i = tid; i < ROWS * 128; i += NT) {
    const int r = i >> 7, c = i & 127;
    float v = 0.f;
    const size_t xb = (size_t)(row0 + r) * INW;
    if (c < 72)            v = x[xb + c];
    else if (c < 77)       v = x[xb + 72 + 5 * a + (c - 72)];
    else if (c >= 96 && c < 106) {
      const int o = c - 96;
      v = x[xb + 72 + (o < 5 * a ? o : o + 5)];
    }
    A[aidx(r, c)] = (_Float16)v;
  }
  __syncthreads();

  // ---- fc2 (K=32 @ col 96) and fc1 (K=96 @ col 0), both linear ----
  f32x4 accD[2][4], accE[2][4];
  gemmT<1>(A, ws + O_FC2, bfc2, 96, l15, l4, rbase, cbase, accD);
  gemmT<3>(A, ws + O_FC1, bfc1, 0,  l15, l4, rbase, cbase, accE);
  __syncthreads();

  writeA(A, accD, l15, l4, rbase, cbase, false);   // A := dec_in
  __syncthreads();

  f32x4 acc[2][4];
  gemmT<8>(A, ws + O_DEC, bdec, 0, l15, l4, rbase, cbase, acc);  // dec_H pre-relu
  half2v dpk[2][4][2];
#pragma unroll
  for (int mt = 0; mt < 2; ++mt)
#pragma unroll
    for (int nt = 0; nt < 4; ++nt)
#pragma unroll
      for (int rh = 0; rh < 2; ++rh)
        dpk[mt][nt][rh] = half2v{
            (_Float16)fmaxf(acc[mt][nt][2 * rh], 0.f),
            (_Float16)fmaxf(acc[mt][nt][2 * rh + 1], 0.f) };
  __syncthreads();

  writeA(A, accE, l15, l4, rbase, cbase, false);   // A := enc_in
  __syncthreads();
  gemmT<8>(A, ws + O_ENC, benc, 0, l15, l4, rbase, cbase, acc);  // enc_h
  __syncthreads();
  writeA(A, acc, l15, l4, rbase, cbase, true);     // A := relu(enc_h)
  __syncthreads();

  // ---- heads + online softmax (reference = head-0 score) ----
  f32x4 ctx[2][4];
#pragma unroll
  for (int mt = 0; mt < 2; ++mt)
#pragma unroll
    for (int nt = 0; nt < 4; ++nt) ctx[mt][nt] = { 0.f, 0.f, 0.f, 0.f };
  float s0[2][4], lsum[2][4];

  for (int h = 0; h < 8; ++h) {
    gemmT<8>(A, ws + O_HDS + (long)h * 65536, bhds + h * 256,
             0, l15, l4, rbase, cbase, acc);
#pragma unroll
    for (int mt = 0; mt < 2; ++mt)
#pragma unroll
      for (int nt = 0; nt < 4; ++nt)
#pragma unroll
        for (int r = 0; r < 4; ++r) acc[mt][nt][r] = fmaxf(acc[mt][nt][r], 0.f);

    // score partials over this wave's 64 cols
    float p[2][4];
#pragma unroll
    for (int mt = 0; mt < 2; ++mt)
#pragma unroll
      for (int r = 0; r < 4; ++r) {
        float v = 0.f;
#pragma unroll
        for (int nt = 0; nt < 4; ++nt)
          v = fmaf(acc[mt][nt][r], (float)dpk[mt][nt][r >> 1][r & 1], v);
        p[mt][r] = v;
      }
    // reduce across the 16 lanes sharing l4 (xor of low-4 bits only)
#pragma unroll
    for (int off = 1; off < 16; off <<= 1)
#pragma unroll
      for (int mt = 0; mt < 2; ++mt)
#pragma unroll
        for (int r = 0; r < 4; ++r)
          p[mt][r] += __shfl_xor(p[mt][r], off, 64);
    if (l15 == 0) {
#pragma unroll
      for (int mt = 0; mt < 2; ++mt)
#pragma unroll
        for (int r = 0; r < 4; ++r)
          sp[h & 1][wc][rbase + mt * 16 + l4 * 4 + r] = p[mt][r];
    }
    __syncthreads();
#pragma unroll
    for (int mt = 0; mt < 2; ++mt)
#pragma unroll
      for (int r = 0; r < 4; ++r) {
        const int row = rbase + mt * 16 + l4 * 4 + r;
        float sh = 0.f;
#pragma unroll
        for (int w = 0; w < 4; ++w) sh += sp[h & 1][w][row];
        float wgt;
        if (h == 0) { s0[mt][r] = sh; lsum[mt][r] = 1.f; wgt = 1.f; }
        else {
          wgt = __expf(fminf(sh - s0[mt][r], 70.f));
          lsum[mt][r] += wgt;
        }
#pragma unroll
        for (int nt = 0; nt < 4; ++nt)
          ctx[mt][nt][r] = fmaf(wgt, acc[mt][nt][r], ctx[mt][nt][r]);
      }
    // sp[h&1] reuse at h+2 is protected by head h+1's barrier
  }

#pragma unroll
  for (int mt = 0; mt < 2; ++mt)
#pragma unroll
    for (int r = 0; r < 4; ++r) {
      const float inv = 1.f / lsum[mt][r];
#pragma unroll
      for (int nt = 0; nt < 4; ++nt) ctx[mt][nt][r] *= inv;
    }
  // all A reads (head-7 gemm) completed before the h=7 barrier
  writeA(A, ctx, l15, l4, rbase, cbase, false);    // A := context
  __syncthreads();

  // ---- fc3 (+relu) then @ Wq ----
  gemmT<8>(A, ws + O_FC3, bfc3, 0, l15, l4, rbase, cbase, acc);
  float wq[4];
#pragma unroll
  for (int nt = 0; nt < 4; ++nt) wq[nt] = Wq[cbase + nt * 16 + l15];
  float p[2][4];
#pragma unroll
  for (int mt = 0; mt < 2; ++mt)
#pragma unroll
    for (int r = 0; r < 4; ++r) {
      float v = 0.f;
#pragma unroll
      for (int nt = 0; nt < 4; ++nt)
        v = fmaf(fmaxf(acc[mt][nt][r], 0.f), wq[nt], v);
      p[mt][r] = v;
    }
#pragma unroll
  for (int off = 1; off < 16; off <<= 1)
#pragma unroll
    for (int mt = 0; mt < 2; ++mt)
#pragma unroll
      for (int r = 0; r < 4; ++r)
        p[mt][r] += __shfl_xor(p[mt][r], off, 64);
  if (l15 == 0) {
#pragma unroll
    for (int mt = 0; mt < 2; ++mt)
#pragma unroll
      for (int r = 0; r < 4; ++r)
        sp[0][wc][rbase + mt * 16 + l4 * 4 + r] = p[mt][r];
  }
  __syncthreads();
  if (tid < ROWS) {
    float v = bq[0];
#pragma unroll
    for (int w = 0; w < 4; ++w) v += sp[0][w][tid];
    out[row0 + tid] = v;
  }
}

}  // namespace

extern "C" void kernel_launch(void* const* d_in, const int* in_sizes, int n_in,
                              void* d_out, int out_size, void* d_ws, size_t ws_size,
                              hipStream_t stream) {
  const float* x    = (const float*)d_in[0];
  const float* Wfc1 = (const float*)d_in[1];
  const float* bfc1 = (const float*)d_in[2];
  const float* Wfc2 = (const float*)d_in[3];
  const float* bfc2 = (const float*)d_in[4];
  const float* Wenc = (const float*)d_in[5];
  const float* benc = (const float*)d_in[6];
  const float* Whds = (const float*)d_in[7];
  const float* bhds = (const float*)d_in[8];
  const float* Wdec = (const float*)d_in[9];
  const float* bdec = (const float*)d_in[10];
  const float* Wfc3 = (const float*)d_in[11];
  const float* bfc3 = (const float*)d_in[12];
  const float* Wq   = (const float*)d_in[13];
  const float* bq   = (const float*)d_in[14];
  const int*  agent = (const int*)d_in[15];
  float* out = (float*)d_out;
  _Float16* ws = (_Float16*)d_ws;

  const int Bn = in_sizes[0] / INW;         // 32768
  const int grid = Bn / ROWS;               // 512 blocks

  prep_w<<<(int)((W_TOTAL / 4 + 255) / 256), 256, 0, stream>>>(
      Wfc1, Wfc2, Wenc, Whds, Wdec, Wfc3, ws);
  fused_mfma<<<grid, NT, 0, stream>>>(x, bfc1, bfc2, benc, bhds, bdec, bfc3,
                                      Wq, bq, agent, ws, out);
}

// Round 5
// 166.797 us; speedup vs baseline: 1.3299x; 1.3299x over previous
//
#include <hip/hip_runtime.h>
#include <hip/hip_bf16.h>

typedef _Float16 half8 __attribute__((ext_vector_type(8)));
typedef _Float16 half4 __attribute__((ext_vector_type(4)));
typedef _Float16 half2v __attribute__((ext_vector_type(2)));
typedef float f32x4 __attribute__((ext_vector_type(4)));

namespace {

constexpr int INW  = 87;
constexpr int ROWS = 64;    // rows per block
constexpr int NT   = 512;   // 8 waves: 2 row-waves x 4 col-waves

// ws layout (fp16 halves), n-major [256][Kpad], all 16B aligned
constexpr long O_WE  = 0;       // [256][96]: k<77 fold(Wfc1@Wenc), k==77 bias row
constexpr long O_WD  = 24576;   // [256][32]: k<10 fold(Wfc2@Wdec), k==10 bias row
constexpr long O_HDS = 32768;   // 8 x [256][256]
constexpr long O_FC3 = 557056;  // [256][256]
constexpr long CONV_TOTAL = 589824;  // halves for hds+fc3

__device__ __forceinline__ int aidx(int row, int col) {
  return row * 256 + ((((col >> 3) ^ (row & 7)) << 3) | (col & 7));
}

// ---------------- prep: fold enc chain:  WE[n][k] ----------------
__global__ __launch_bounds__(256)
void prep_fold_enc(const float* __restrict__ Wfc1, const float* __restrict__ bfc1,
                   const float* __restrict__ Wenc, const float* __restrict__ benc,
                   _Float16* __restrict__ ws)
{
  const int t = (int)blockIdx.x * 256 + (int)threadIdx.x;   // 96*256 threads
  const int n = t & 255, k = t >> 8;                        // k 0..95
  float acc = 0.f;
  if (k < 77) {
    for (int m = 0; m < 256; ++m) acc += Wfc1[(size_t)k * 256 + m] * Wenc[(size_t)m * 256 + n];
  } else if (k == 77) {
    for (int m = 0; m < 256; ++m) acc += bfc1[m] * Wenc[(size_t)m * 256 + n];
    acc += benc[n];
  }
  ws[O_WE + (long)n * 96 + k] = (_Float16)acc;
}

// ---------------- prep: fold dec chain:  WD[n][k] ----------------
__global__ __launch_bounds__(256)
void prep_fold_dec(const float* __restrict__ Wfc2, const float* __restrict__ bfc2,
                   const float* __restrict__ Wdec, const float* __restrict__ bdec,
                   _Float16* __restrict__ ws)
{
  const int t = (int)blockIdx.x * 256 + (int)threadIdx.x;   // 32*256 threads
  const int n = t & 255, k = t >> 8;                        // k 0..31
  float acc = 0.f;
  if (k < 10) {
    for (int m = 0; m < 256; ++m) acc += Wfc2[(size_t)k * 256 + m] * Wdec[(size_t)m * 256 + n];
  } else if (k == 10) {
    for (int m = 0; m < 256; ++m) acc += bfc2[m] * Wdec[(size_t)m * 256 + n];
    acc += bdec[n];
  }
  ws[O_WD + (long)n * 32 + k] = (_Float16)acc;
}

// ---------------- prep: transpose+convert heads & fc3 ----------------
__global__ __launch_bounds__(256)
void prep_conv(const float* __restrict__ Whds, const float* __restrict__ Wfc3,
               _Float16* __restrict__ ws)
{
  const long t = (long)blockIdx.x * 256 + threadIdx.x;
  const long e = t * 4;
  if (e >= CONV_TOTAL) return;
  const int h = (int)(e >> 16);                 // 0..8 (8 == fc3)
  const float* src = (h < 8) ? (Whds + ((long)h << 16)) : Wfc3;
  const long le = e & 65535;
  const int n = (int)(le >> 8), k0 = (int)(le & 255);
  half4 v;
#pragma unroll
  for (int j = 0; j < 4; ++j)
    v[j] = (_Float16)src[(size_t)(k0 + j) * 256 + n];
  *(half4*)&ws[O_HDS + e] = v;
}

// =========================== main fused kernel ===========================
__global__ __launch_bounds__(NT, 4)
void fused_mfma(const float* __restrict__ x,
                const float* __restrict__ bhds,
                const float* __restrict__ bfc3,
                const float* __restrict__ Wq,  const float* __restrict__ bq,
                const int* __restrict__ agent,
                const _Float16* __restrict__ ws,
                float* __restrict__ out)
{
  __shared__ _Float16 A[ROWS * 256];        // 32 KB
  __shared__ _Float16 Bst[2][8192];         // 2 x 16 KB (256n x 32k slice)
  __shared__ float sp[2][4][ROWS];          // 2 KB

  const int tid  = (int)threadIdx.x;
  const int lane = tid & 63;
  const int wave = tid >> 6;
  const int wr   = wave >> 2;       // 0..1 : 32-row stripe
  const int wc   = wave & 3;        // 0..3 : 64-col stripe
  const int l15  = lane & 15;
  const int l4   = lane >> 4;
  const int rbase = wr * 32;
  const int cbase = wc * 64;
  const int row0 = (int)blockIdx.x * ROWS;
  const int a = agent[0];

  int par = 1;   // next stage writes Bst[par^1]

  // stage a 32-k slice of W[n][Klen] into Bst[par^1], pre-swizzled source
  auto stageNext = [&](const _Float16* wb, int Klen, int k0) {
    _Float16* dst = &Bst[par ^ 1][0];
#pragma unroll
    for (int i = 0; i < 2; ++i) {
      const int p = tid + i * 512;                 // phys chunk 0..1023
      const int n = p >> 2;
      const int j = (p & 3) ^ ((n >> 2) & 3);      // logical k-chunk
      const _Float16* src = wb + (long)n * Klen + k0 + j * 8;
      auto* gp = (const __attribute__((address_space(1))) unsigned int*)src;
      auto* lp = (__attribute__((address_space(3))) unsigned int*)(dst + (long)p * 8);
      __builtin_amdgcn_global_load_lds(gp, lp, 16, 0, 0);
    }
  };

  // one 32-k slice of MFMA work from Bst[par]; A cols acol..acol+31
  auto sliceCompute = [&](int acol, f32x4 (&acc)[2][4]) {
    const _Float16* bufc = &Bst[par][0];
    half8 af[2], bf[4];
#pragma unroll
    for (int mt = 0; mt < 2; ++mt) {
      const int row = rbase + mt * 16 + l15;
      const int cch = (acol >> 3) + l4;            // col chunk
      af[mt] = *(const half8*)&A[row * 256 + ((cch ^ (row & 7)) << 3)];
    }
#pragma unroll
    for (int nt = 0; nt < 4; ++nt) {
      const int n = cbase + nt * 16 + l15;
      const int p = n * 4 + (l4 ^ ((n >> 2) & 3));
      bf[nt] = *(const half8*)&bufc[(long)p * 8];
    }
#pragma unroll
    for (int mt = 0; mt < 2; ++mt)
#pragma unroll
      for (int nt = 0; nt < 4; ++nt)
        acc[mt][nt] = __builtin_amdgcn_mfma_f32_16x16x32_f16(
            af[mt], bf[nt], acc[mt][nt], 0, 0, 0);
  };

  auto zeroAcc = [&](f32x4 (&acc)[2][4]) {
#pragma unroll
    for (int mt = 0; mt < 2; ++mt)
#pragma unroll
      for (int nt = 0; nt < 4; ++nt) acc[mt][nt] = { 0.f, 0.f, 0.f, 0.f };
  };

  // KS slices; prefetches next GEMM's slice 0 (nwb) during the last slice
  auto gemmRun = [&](const _Float16* wb, int Klen, int KS, int acol0,
                     f32x4 (&acc)[2][4], const _Float16* nwb, int nKlen) {
    for (int s = 0; s < KS; ++s) {
      if (s + 1 < KS)   stageNext(wb, Klen, (s + 1) * 32);
      else if (nwb)     stageNext(nwb, nKlen, 0);
      sliceCompute(acol0 + s * 32, acc);
      __syncthreads();
      par ^= 1;
    }
  };

  auto writeA = [&](const f32x4 (&acc)[2][4], bool relu) {
#pragma unroll
    for (int mt = 0; mt < 2; ++mt)
#pragma unroll
      for (int nt = 0; nt < 4; ++nt)
#pragma unroll
        for (int r = 0; r < 4; ++r) {
          float v = acc[mt][nt][r];
          if (relu) v = fmaxf(v, 0.f);
          A[aidx(rbase + mt * 16 + l4 * 4 + r, cbase + nt * 16 + l15)] = (_Float16)v;
        }
  };

  // ---- build A0 (cols 0..127): enc-in 0..76, 77=1, dec-others 96..105, 106=1 ----
  for (int i = tid; i < ROWS * 128; i += NT) {
    const int r = i >> 7, c = i & 127;
    float v = 0.f;
    const size_t xb = (size_t)(row0 + r) * INW;
    if (c < 72)            v = x[xb + c];
    else if (c < 77)       v = x[xb + 72 + 5 * a + (c - 72)];
    else if (c == 77)      v = 1.f;
    else if (c >= 96 && c < 106) {
      const int o = c - 96;
      v = x[xb + 72 + (o < 5 * a ? o : o + 5)];
    }
    else if (c == 106)     v = 1.f;
    A[aidx(r, c)] = (_Float16)v;
  }
  stageNext(ws + O_WE, 96, 0);        // slice E0 -> Bst[0]
  __syncthreads();
  par ^= 1;                           // par = 0

  // ---- enc_h pre-relu (folded, K=96) and dec_H pre-relu (folded, K=32) ----
  f32x4 accE[2][4], acc[2][4];
  zeroAcc(accE);
  gemmRun(ws + O_WE, 96, 3, 0, accE, ws + O_WD, 32);
  zeroAcc(acc);
  gemmRun(ws + O_WD, 32, 1, 96, acc, ws + O_HDS, 256);

  half2v dpk[2][4][2];                // dec_H = relu, packed fp16
#pragma unroll
  for (int mt = 0; mt < 2; ++mt)
#pragma unroll
    for (int nt = 0; nt < 4; ++nt)
#pragma unroll
      for (int rh = 0; rh < 2; ++rh)
        dpk[mt][nt][rh] = half2v{
            (_Float16)fmaxf(acc[mt][nt][2 * rh], 0.f),
            (_Float16)fmaxf(acc[mt][nt][2 * rh + 1], 0.f) };

  writeA(accE, true);                 // A := enc_h = relu(...)
  __syncthreads();

  // ---- heads + online softmax (reference = head-0 score) ----
  f32x4 ctx[2][4];
  zeroAcc(ctx);
  float s0[2][4], lsum[2][4];

  for (int h = 0; h < 8; ++h) {
    float bh[4];
#pragma unroll
    for (int nt = 0; nt < 4; ++nt) bh[nt] = bhds[h * 256 + cbase + nt * 16 + l15];

    zeroAcc(acc);
    const _Float16* nw = (h < 7) ? (ws + O_HDS + (long)(h + 1) * 65536) : (ws + O_FC3);
    gemmRun(ws + O_HDS + (long)h * 65536, 256, 8, 0, acc, nw, 256);

#pragma unroll
    for (int mt = 0; mt < 2; ++mt)
#pragma unroll
      for (int nt = 0; nt < 4; ++nt)
#pragma unroll
        for (int r = 0; r < 4; ++r)
          acc[mt][nt][r] = fmaxf(acc[mt][nt][r] + bh[nt], 0.f);

    float p[2][4];
#pragma unroll
    for (int mt = 0; mt < 2; ++mt)
#pragma unroll
      for (int r = 0; r < 4; ++r) {
        float v = 0.f;
#pragma unroll
        for (int nt = 0; nt < 4; ++nt)
          v = fmaf(acc[mt][nt][r], (float)dpk[mt][nt][r >> 1][r & 1], v);
        p[mt][r] = v;
      }
#pragma unroll
    for (int off = 1; off < 16; off <<= 1)
#pragma unroll
      for (int mt = 0; mt < 2; ++mt)
#pragma unroll
        for (int r = 0; r < 4; ++r)
          p[mt][r] += __shfl_xor(p[mt][r], off, 64);
    if (l15 == 0) {
#pragma unroll
      for (int mt = 0; mt < 2; ++mt)
#pragma unroll
        for (int r = 0; r < 4; ++r)
          sp[h & 1][wc][rbase + mt * 16 + l4 * 4 + r] = p[mt][r];
    }
    __syncthreads();
#pragma unroll
    for (int mt = 0; mt < 2; ++mt)
#pragma unroll
      for (int r = 0; r < 4; ++r) {
        const int row = rbase + mt * 16 + l4 * 4 + r;
        float sh = sp[h & 1][0][row] + sp[h & 1][1][row]
                 + sp[h & 1][2][row] + sp[h & 1][3][row];
        float wgt;
        if (h == 0) { s0[mt][r] = sh; lsum[mt][r] = 1.f; wgt = 1.f; }
        else {
          wgt = __expf(fminf(sh - s0[mt][r], 70.f));
          lsum[mt][r] += wgt;
        }
#pragma unroll
        for (int nt = 0; nt < 4; ++nt)
          ctx[mt][nt][r] = fmaf(wgt, acc[mt][nt][r], ctx[mt][nt][r]);
      }
    // sp[h&1] reused at h+2, protected by head h+1's slice barriers
  }

#pragma unroll
  for (int mt = 0; mt < 2; ++mt)
#pragma unroll
    for (int r = 0; r < 4; ++r) {
      const float inv = 1.f / lsum[mt][r];
#pragma unroll
      for (int nt = 0; nt < 4; ++nt) ctx[mt][nt][r] *= inv;
    }
  writeA(ctx, false);                 // A := context
  __syncthreads();

  // ---- fc3 (+bias+relu) then @ Wq ----
  float bf3[4], wq[4];
#pragma unroll
  for (int nt = 0; nt < 4; ++nt) {
    bf3[nt] = bfc3[cbase + nt * 16 + l15];
    wq[nt]  = Wq[cbase + nt * 16 + l15];
  }
  zeroAcc(acc);
  gemmRun(ws + O_FC3, 256, 8, 0, acc, nullptr, 0);

  float p[2][4];
#pragma unroll
  for (int mt = 0; mt < 2; ++mt)
#pragma unroll
    for (int r = 0; r < 4; ++r) {
      float v = 0.f;
#pragma unroll
      for (int nt = 0; nt < 4; ++nt)
        v = fmaf(fmaxf(acc[mt][nt][r] + bf3[nt], 0.f), wq[nt], v);
      p[mt][r] = v;
    }
#pragma unroll
  for (int off = 1; off < 16; off <<= 1)
#pragma unroll
    for (int mt = 0; mt < 2; ++mt)
#pragma unroll
      for (int r = 0; r < 4; ++r)
        p[mt][r] += __shfl_xor(p[mt][r], off, 64);
  if (l15 == 0) {
#pragma unroll
    for (int mt = 0; mt < 2; ++mt)
#pragma unroll
      for (int r = 0; r < 4; ++r)
        sp[0][wc][rbase + mt * 16 + l4 * 4 + r] = p[mt][r];
  }
  __syncthreads();
  if (tid < ROWS) {
    out[row0 + tid] = bq[0] + sp[0][0][tid] + sp[0][1][tid]
                    + sp[0][2][tid] + sp[0][3][tid];
  }
}

}  // namespace

extern "C" void kernel_launch(void* const* d_in, const int* in_sizes, int n_in,
                              void* d_out, int out_size, void* d_ws, size_t ws_size,
                              hipStream_t stream) {
  const float* x    = (const float*)d_in[0];
  const float* Wfc1 = (const float*)d_in[1];
  const float* bfc1 = (const float*)d_in[2];
  const float* Wfc2 = (const float*)d_in[3];
  const float* bfc2 = (const float*)d_in[4];
  const float* Wenc = (const float*)d_in[5];
  const float* benc = (const float*)d_in[6];
  const float* Whds = (const float*)d_in[7];
  const float* bhds = (const float*)d_in[8];
  const float* Wdec = (const float*)d_in[9];
  const float* bdec = (const float*)d_in[10];
  const float* Wfc3 = (const float*)d_in[11];
  const float* bfc3 = (const float*)d_in[12];
  const float* Wq   = (const float*)d_in[13];
  const float* bq   = (const float*)d_in[14];
  const int*  agent = (const int*)d_in[15];
  float* out = (float*)d_out;
  _Float16* ws = (_Float16*)d_ws;

  const int Bn = in_sizes[0] / INW;         // 32768
  const int grid = Bn / ROWS;               // 512 blocks

  prep_fold_enc<<<96, 256, 0, stream>>>(Wfc1, bfc1, Wenc, benc, ws);
  prep_fold_dec<<<32, 256, 0, stream>>>(Wfc2, bfc2, Wdec, bdec, ws);
  prep_conv<<<(int)((CONV_TOTAL / 4 + 255) / 256), 256, 0, stream>>>(Whds, Wfc3, ws);
  fused_mfma<<<grid, NT, 0, stream>>>(x, bhds, bfc3, Wq, bq, agent, ws, out);
}

// Round 6
// 142.147 us; speedup vs baseline: 1.5605x; 1.1734x over previous
//
#include <hip/hip_runtime.h>
#include <hip/hip_bf16.h>

typedef _Float16 half8 __attribute__((ext_vector_type(8)));
typedef _Float16 half4 __attribute__((ext_vector_type(4)));
typedef _Float16 half2v __attribute__((ext_vector_type(2)));
typedef float f32x4 __attribute__((ext_vector_type(4)));

namespace {

constexpr int INW  = 87;
constexpr int ROWS = 64;    // rows per block
constexpr int NT   = 512;   // 8 waves: 2 row-waves x 4 col-waves
constexpr int NSLICES = 76; // 3(WE) + 1(WD) + 64(heads) + 8(fc3)

// ws layout (fp16 halves), n-major [256][Kpad], all 16B aligned
constexpr long O_WE  = 0;       // [256][96]: k<77 fold(Wfc1@Wenc), k==77 bias row
constexpr long O_WD  = 24576;   // [256][32]: k<10 fold(Wfc2@Wdec), k==10 bias row
constexpr long O_HDS = 32768;   // 8 x [256][256]
constexpr long O_FC3 = 557056;  // [256][256]
constexpr long CONV_TOTAL = 589824;  // halves for hds+fc3

__device__ __forceinline__ int aidx(int row, int col) {
  return row * 256 + ((((col >> 3) ^ (row & 7)) << 3) | (col & 7));
}

// ---------------- prep: fold enc chain:  WE[n][k] ----------------
__global__ __launch_bounds__(256)
void prep_fold_enc(const float* __restrict__ Wfc1, const float* __restrict__ bfc1,
                   const float* __restrict__ Wenc, const float* __restrict__ benc,
                   _Float16* __restrict__ ws)
{
  const int t = (int)blockIdx.x * 256 + (int)threadIdx.x;   // 96*256 threads
  const int n = t & 255, k = t >> 8;                        // k 0..95
  float acc = 0.f;
  if (k < 77) {
    for (int m = 0; m < 256; ++m) acc += Wfc1[(size_t)k * 256 + m] * Wenc[(size_t)m * 256 + n];
  } else if (k == 77) {
    for (int m = 0; m < 256; ++m) acc += bfc1[m] * Wenc[(size_t)m * 256 + n];
    acc += benc[n];
  }
  ws[O_WE + (long)n * 96 + k] = (_Float16)acc;
}

// ---------------- prep: fold dec chain:  WD[n][k] ----------------
__global__ __launch_bounds__(256)
void prep_fold_dec(const float* __restrict__ Wfc2, const float* __restrict__ bfc2,
                   const float* __restrict__ Wdec, const float* __restrict__ bdec,
                   _Float16* __restrict__ ws)
{
  const int t = (int)blockIdx.x * 256 + (int)threadIdx.x;   // 32*256 threads
  const int n = t & 255, k = t >> 8;                        // k 0..31
  float acc = 0.f;
  if (k < 10) {
    for (int m = 0; m < 256; ++m) acc += Wfc2[(size_t)k * 256 + m] * Wdec[(size_t)m * 256 + n];
  } else if (k == 10) {
    for (int m = 0; m < 256; ++m) acc += bfc2[m] * Wdec[(size_t)m * 256 + n];
    acc += bdec[n];
  }
  ws[O_WD + (long)n * 32 + k] = (_Float16)acc;
}

// ---------------- prep: transpose+convert heads & fc3 ----------------
__global__ __launch_bounds__(256)
void prep_conv(const float* __restrict__ Whds, const float* __restrict__ Wfc3,
               _Float16* __restrict__ ws)
{
  const long t = (long)blockIdx.x * 256 + threadIdx.x;
  const long e = t * 4;
  if (e >= CONV_TOTAL) return;
  const int h = (int)(e >> 16);                 // 0..8 (8 == fc3)
  const float* src = (h < 8) ? (Whds + ((long)h << 16)) : Wfc3;
  const long le = e & 65535;
  const int n = (int)(le >> 8), k0 = (int)(le & 255);
  half4 v;
#pragma unroll
  for (int j = 0; j < 4; ++j)
    v[j] = (_Float16)src[(size_t)(k0 + j) * 256 + n];
  *(half4*)&ws[O_HDS + e] = v;
}

// counted-vmcnt barriers: keep newest prefetch (2 loads/thread) in flight
__device__ __forceinline__ void sync_vm2() {
  asm volatile("s_waitcnt vmcnt(2) lgkmcnt(0)" ::: "memory");
  __builtin_amdgcn_s_barrier();
}
__device__ __forceinline__ void sync_vm0() {
  asm volatile("s_waitcnt vmcnt(0) lgkmcnt(0)" ::: "memory");
  __builtin_amdgcn_s_barrier();
}

struct SliceD { const _Float16* base; int Klen; int k0; };
__device__ __forceinline__ SliceD slice_desc(int i, const _Float16* ws) {
  if (i < 3)  return { ws + O_WE, 96, i * 32 };
  if (i == 3) return { ws + O_WD, 32, 0 };
  if (i < 68) { const int t = i - 4;
                return { ws + O_HDS + (long)(t >> 3) * 65536, 256, (t & 7) * 32 }; }
  return { ws + O_FC3, 256, (i - 68) * 32 };
}

// =========================== main fused kernel ===========================
__global__ __launch_bounds__(NT)
void fused_mfma(const float* __restrict__ x,
                const float* __restrict__ bhds,
                const float* __restrict__ bfc3,
                const float* __restrict__ Wq,  const float* __restrict__ bq,
                const int* __restrict__ agent,
                const _Float16* __restrict__ ws,
                float* __restrict__ out)
{
  __shared__ _Float16 A[ROWS * 256];        // 32 KB
  __shared__ _Float16 Bst[3][8192];         // 3 x 16 KB (256n x 32k slice)
  __shared__ float sp[2][4][ROWS];          // 2 KB

  const int tid  = (int)threadIdx.x;
  const int lane = tid & 63;
  const int wave = tid >> 6;
  const int wr   = wave >> 2;       // 0..1 : 32-row stripe
  const int wc   = wave & 3;        // 0..3 : 64-col stripe
  const int l15  = lane & 15;
  const int l4   = lane >> 4;
  const int rbase = wr * 32;
  const int cbase = wc * 64;
  const int row0 = (int)blockIdx.x * ROWS;
  const int a = agent[0];

  int cur = 0;   // slice being computed next
  int pf  = 0;   // next slice to prefetch

  auto issuePF = [&](int i) {
    const SliceD d = slice_desc(i, ws);
    _Float16* dst = &Bst[i % 3][0];
#pragma unroll
    for (int ii = 0; ii < 2; ++ii) {
      const int p = tid + ii * 512;                // phys chunk 0..1023
      const int n = p >> 2;
      const int j = (p & 3) ^ ((n >> 2) & 3);      // logical k-chunk
      const _Float16* src = d.base + (long)n * d.Klen + d.k0 + j * 8;
      auto* gp = (const __attribute__((address_space(1))) unsigned int*)src;
      auto* lp = (__attribute__((address_space(3))) unsigned int*)(dst + (long)p * 8);
      __builtin_amdgcn_global_load_lds(gp, lp, 16, 0, 0);
    }
  };

  auto sliceCompute = [&](int acol, f32x4 (&acc)[2][4]) {
    const _Float16* bufc = &Bst[cur % 3][0];
    half8 af[2], bf[4];
#pragma unroll
    for (int mt = 0; mt < 2; ++mt) {
      const int row = rbase + mt * 16 + l15;
      const int cch = (acol >> 3) + l4;            // col chunk
      af[mt] = *(const half8*)&A[row * 256 + ((cch ^ (row & 7)) << 3)];
    }
#pragma unroll
    for (int nt = 0; nt < 4; ++nt) {
      const int n = cbase + nt * 16 + l15;
      const int p = n * 4 + (l4 ^ ((n >> 2) & 3));
      bf[nt] = *(const half8*)&bufc[(long)p * 8];
    }
#pragma unroll
    for (int mt = 0; mt < 2; ++mt)
#pragma unroll
      for (int nt = 0; nt < 4; ++nt)
        acc[mt][nt] = __builtin_amdgcn_mfma_f32_16x16x32_f16(
            af[mt], bf[nt], acc[mt][nt], 0, 0, 0);
  };

  auto zeroAcc = [&](f32x4 (&acc)[2][4]) {
#pragma unroll
    for (int mt = 0; mt < 2; ++mt)
#pragma unroll
      for (int nt = 0; nt < 4; ++nt) acc[mt][nt] = { 0.f, 0.f, 0.f, 0.f };
  };

  // run KS slices of the current GEMM group; pipeline invariant: entering,
  // Bst[cur%3] is ready, slice cur+1's DMA is in flight, pf == cur+2.
  auto runSlices = [&](int KS, int acol0, f32x4 (&acc)[2][4]) {
    for (int s = 0; s < KS; ++s) {
      const bool issued = (pf < NSLICES);
      if (issued) issuePF(pf++);
      sliceCompute(acol0 + s * 32, acc);
      if (issued) sync_vm2(); else sync_vm0();
      ++cur;
    }
  };

  auto writeA = [&](const f32x4 (&acc)[2][4], bool relu) {
#pragma unroll
    for (int mt = 0; mt < 2; ++mt)
#pragma unroll
      for (int nt = 0; nt < 4; ++nt)
#pragma unroll
        for (int r = 0; r < 4; ++r) {
          float v = acc[mt][nt][r];
          if (relu) v = fmaxf(v, 0.f);
          A[aidx(rbase + mt * 16 + l4 * 4 + r, cbase + nt * 16 + l15)] = (_Float16)v;
        }
  };

  // ---- build A0 (cols 0..127): enc-in 0..76, 77=1, dec-others 96..105, 106=1 ----
  for (int i = tid; i < ROWS * 128; i += NT) {
    const int r = i >> 7, c = i & 127;
    float v = 0.f;
    const size_t xb = (size_t)(row0 + r) * INW;
    if (c < 72)            v = x[xb + c];
    else if (c < 77)       v = x[xb + 72 + 5 * a + (c - 72)];
    else if (c == 77)      v = 1.f;
    else if (c >= 96 && c < 106) {
      const int o = c - 96;
      v = x[xb + 72 + (o < 5 * a ? o : o + 5)];
    }
    else if (c == 106)     v = 1.f;
    A[aidx(r, c)] = (_Float16)v;
  }
  issuePF(0); issuePF(1); pf = 2;
  __syncthreads();                    // full drain once (prologue only)

  // ---- enc_h pre-relu (folded, K=96) and dec_H pre-relu (folded, K=32) ----
  f32x4 accE[2][4], acc[2][4];
  zeroAcc(accE);
  runSlices(3, 0, accE);
  zeroAcc(acc);
  runSlices(1, 96, acc);

  half2v dpk[2][4][2];                // dec_H = relu, packed fp16
#pragma unroll
  for (int mt = 0; mt < 2; ++mt)
#pragma unroll
    for (int nt = 0; nt < 4; ++nt)
#pragma unroll
      for (int rh = 0; rh < 2; ++rh)
        dpk[mt][nt][rh] = half2v{
            (_Float16)fmaxf(acc[mt][nt][2 * rh], 0.f),
            (_Float16)fmaxf(acc[mt][nt][2 * rh + 1], 0.f) };

  writeA(accE, true);                 // A := enc_h = relu(...)
  sync_vm2();                         // lgkmcnt(0)+barrier makes A visible

  // ---- heads + online softmax (reference = head-0 score) ----
  f32x4 ctx[2][4];
  zeroAcc(ctx);
  float s0[2][4], lsum[2][4];

  for (int h = 0; h < 8; ++h) {
    float bh[4];
#pragma unroll
    for (int nt = 0; nt < 4; ++nt) bh[nt] = bhds[h * 256 + cbase + nt * 16 + l15];

    zeroAcc(acc);
    runSlices(8, 0, acc);

#pragma unroll
    for (int mt = 0; mt < 2; ++mt)
#pragma unroll
      for (int nt = 0; nt < 4; ++nt)
#pragma unroll
        for (int r = 0; r < 4; ++r)
          acc[mt][nt][r] = fmaxf(acc[mt][nt][r] + bh[nt], 0.f);

    float p[2][4];
#pragma unroll
    for (int mt = 0; mt < 2; ++mt)
#pragma unroll
      for (int r = 0; r < 4; ++r) {
        float v = 0.f;
#pragma unroll
        for (int nt = 0; nt < 4; ++nt)
          v = fmaf(acc[mt][nt][r], (float)dpk[mt][nt][r >> 1][r & 1], v);
        p[mt][r] = v;
      }
#pragma unroll
    for (int off = 1; off < 16; off <<= 1)
#pragma unroll
      for (int mt = 0; mt < 2; ++mt)
#pragma unroll
        for (int r = 0; r < 4; ++r)
          p[mt][r] += __shfl_xor(p[mt][r], off, 64);
    if (l15 == 0) {
#pragma unroll
      for (int mt = 0; mt < 2; ++mt)
#pragma unroll
        for (int r = 0; r < 4; ++r)
          sp[h & 1][wc][rbase + mt * 16 + l4 * 4 + r] = p[mt][r];
    }
    sync_vm2();                       // sp visible; prefetches stay in flight
#pragma unroll
    for (int mt = 0; mt < 2; ++mt)
#pragma unroll
      for (int r = 0; r < 4; ++r) {
        const int row = rbase + mt * 16 + l4 * 4 + r;
        const float sh = sp[h & 1][0][row] + sp[h & 1][1][row]
                       + sp[h & 1][2][row] + sp[h & 1][3][row];
        float wgt;
        if (h == 0) { s0[mt][r] = sh; lsum[mt][r] = 1.f; wgt = 1.f; }
        else {
          wgt = __expf(fminf(sh - s0[mt][r], 70.f));
          lsum[mt][r] += wgt;
        }
#pragma unroll
        for (int nt = 0; nt < 4; ++nt)
          ctx[mt][nt][r] = fmaf(wgt, acc[mt][nt][r], ctx[mt][nt][r]);
      }
    // sp[h&1] reused at h+2, protected by head h+1's 8 slice barriers
  }

#pragma unroll
  for (int mt = 0; mt < 2; ++mt)
#pragma unroll
    for (int r = 0; r < 4; ++r) {
      const float inv = 1.f / lsum[mt][r];
#pragma unroll
      for (int nt = 0; nt < 4; ++nt) ctx[mt][nt][r] *= inv;
    }
  writeA(ctx, false);                 // A := context
  sync_vm2();

  // ---- fc3 (+bias+relu) then @ Wq ----
  float bf3[4], wq[4];
#pragma unroll
  for (int nt = 0; nt < 4; ++nt) {
    bf3[nt] = bfc3[cbase + nt * 16 + l15];
    wq[nt]  = Wq[cbase + nt * 16 + l15];
  }
  zeroAcc(acc);
  runSlices(8, 0, acc);

  float p[2][4];
#pragma unroll
  for (int mt = 0; mt < 2; ++mt)
#pragma unroll
    for (int r = 0; r < 4; ++r) {
      float v = 0.f;
#pragma unroll
      for (int nt = 0; nt < 4; ++nt)
        v = fmaf(fmaxf(acc[mt][nt][r] + bf3[nt], 0.f), wq[nt], v);
      p[mt][r] = v;
    }
#pragma unroll
  for (int off = 1; off < 16; off <<= 1)
#pragma unroll
    for (int mt = 0; mt < 2; ++mt)
#pragma unroll
      for (int r = 0; r < 4; ++r)
        p[mt][r] += __shfl_xor(p[mt][r], off, 64);
  if (l15 == 0) {
#pragma unroll
    for (int mt = 0; mt < 2; ++mt)
#pragma unroll
      for (int r = 0; r < 4; ++r)
        sp[0][wc][rbase + mt * 16 + l4 * 4 + r] = p[mt][r];
  }
  __syncthreads();
  if (tid < ROWS) {
    out[row0 + tid] = bq[0] + sp[0][0][tid] + sp[0][1][tid]
                    + sp[0][2][tid] + sp[0][3][tid];
  }
}

}  // namespace

extern "C" void kernel_launch(void* const* d_in, const int* in_sizes, int n_in,
                              void* d_out, int out_size, void* d_ws, size_t ws_size,
                              hipStream_t stream) {
  const float* x    = (const float*)d_in[0];
  const float* Wfc1 = (const float*)d_in[1];
  const float* bfc1 = (const float*)d_in[2];
  const float* Wfc2 = (const float*)d_in[3];
  const float* bfc2 = (const float*)d_in[4];
  const float* Wenc = (const float*)d_in[5];
  const float* benc = (const float*)d_in[6];
  const float* Whds = (const float*)d_in[7];
  const float* bhds = (const float*)d_in[8];
  const float* Wdec = (const float*)d_in[9];
  const float* bdec = (const float*)d_in[10];
  const float* Wfc3 = (const float*)d_in[11];
  const float* bfc3 = (const float*)d_in[12];
  const float* Wq   = (const float*)d_in[13];
  const float* bq   = (const float*)d_in[14];
  const int*  agent = (const int*)d_in[15];
  float* out = (float*)d_out;
  _Float16* ws = (_Float16*)d_ws;

  const int Bn = in_sizes[0] / INW;         // 32768
  const int grid = Bn / ROWS;               // 512 blocks

  prep_fold_enc<<<96, 256, 0, stream>>>(Wfc1, bfc1, Wenc, benc, ws);
  prep_fold_dec<<<32, 256, 0, stream>>>(Wfc2, bfc2, Wdec, bdec, ws);
  prep_conv<<<(int)((CONV_TOTAL / 4 + 255) / 256), 256, 0, stream>>>(Whds, Wfc3, ws);
  fused_mfma<<<grid, NT, 0, stream>>>(x, bhds, bfc3, Wq, bq, agent, ws, out);
}